// Round 16
// baseline (171.155 us; speedup 1.0000x reference)
//
#include <hip/hip_runtime.h>
#include <cstdint>
#include <cstddef>

// Problem constants (fixed by the harness): B=4, P=500000, C=32, H=512, W=512.
#define TH 256

// clang ext_vector_type: __builtin_nontemporal_load rejects HIP_vector_type
// (float4) pointers but accepts vectors of scalar types.
typedef float vfloat4 __attribute__((ext_vector_type(4)));

#define PIX_INVALID 0xFFFFFFFFu
#define IDX_EMPTY   0x7FFFFFFFu   // > any pid; uint-min == int-min for >=0

// ---------------------------------------------------------------------------
// f32 <-> bf16 helpers (RNE). Unit-normal features: err ~0.02 << 0.2 thresh.
// (bf16 staging validated R4-R15: harness absmax 0.0 vs np ref.)
// ---------------------------------------------------------------------------
__device__ __forceinline__ unsigned int f32_to_bf16_rne(float x) {
    const unsigned int u = __float_as_uint(x);
    return (u + 0x7FFFu + ((u >> 16) & 1u)) >> 16;   // 16-bit result
}
__device__ __forceinline__ float bf16_bits_to_f32(unsigned int h) {
    return __uint_as_float(h << 16);
}

// ---------------------------------------------------------------------------
// Init: dmin = 0xFFFFFFFF (+inf sentinel; all valid f32 depth bits are
// smaller), idx = 0x7FFFFFFF (INT_MAX sentinel). 8 MB total, ~3 us.
// ---------------------------------------------------------------------------
__global__ void init_zbuf_kernel(uint4* __restrict__ dmin4,
                                 uint4* __restrict__ idx4, int n4)
{
    const int i = blockIdx.x * blockDim.x + threadIdx.x;
    if (i < n4) {
        dmin4[i] = make_uint4(PIX_INVALID, PIX_INVALID, PIX_INVALID, PIX_INVALID);
        idx4[i]  = make_uint4(IDX_EMPTY, IDX_EMPTY, IDX_EMPTY, IDX_EMPTY);
    }
}

// ---------------------------------------------------------------------------
// Projection (shared): reproduces _rasterize_one's math in f32.
// ---------------------------------------------------------------------------
__device__ __forceinline__ bool project_point(
    const float* __restrict__ pc, const float* __restrict__ K,
    const float* __restrict__ E, const float* __restrict__ nf,
    int b, int p, int P, int Hh, int Ww,
    int& pix_out, float& zc_out)
{
    const int i = b * P + p;
    const float x = pc[3 * i + 0];
    const float y = pc[3 * i + 1];
    const float z = pc[3 * i + 2];
    const float* Eb = E + b * 12;
    const float dx = x - Eb[3], dy = y - Eb[7], dz = z - Eb[11];
    const float zc = dx * Eb[2] + dy * Eb[6] + dz * Eb[10];
    const float zs = (zc == 0.0f) ? 1.0f : zc;
    const float* Kb = K + b * 9;
    const float u = Kb[0] * (dx * Eb[0] + dy * Eb[4] + dz * Eb[8]) / zs + Kb[2];
    const float v = Kb[4] * (dx * Eb[1] + dy * Eb[5] + dz * Eb[9]) / zs + Kb[5];
    const int ui = (int)floorf(u);
    const int vi = (int)floorf(v);
    const float nf0 = nf[b * 3 + 0], nf1 = nf[b * 3 + 1];
    const bool valid = (zc > nf0) && (zc < nf1) &&
                       (ui >= 0) && (ui < Ww) && (vi >= 0) && (vi < Hh);
    pix_out = vi * Ww + ui;
    zc_out  = zc;
    return valid;
}

// ---------------------------------------------------------------------------
// FUSED transpose + 32-BIT depth rasterize (R16 change).
// R8-R15 evidence: the 2M 64-bit packed atomics are a ~78 us pipeline floor
// and interfere ~30 us with the streaming phase. Split z-buffer (reference's
// own 2-pass scheme): this kernel only atomicMin's the 32-bit DEPTH BITS
// (positive f32 bits are order-isomorphic to values -> exact f32 min), and
// persists (pix, zcbits) per point for the resolve pass. Atomic bytes halve;
// pid resolution moves to a cheap pass over L3-hot dmin.
//   Phase B: bf16-LDS transpose (16.5 KB, 8 blocks/CU), nontemporal feats
//   reads (R13: +10 us), conflict-free LDS via odd stride 129. TILE=256
//   (512 was neutral-to-worse, R15).
// ---------------------------------------------------------------------------
__global__ void fused_raster_transpose_kernel(
    const float* __restrict__ pc, const float* __restrict__ K,
    const float* __restrict__ E, const float* __restrict__ nf,
    const float* __restrict__ feats,   // (32, B*P)
    unsigned int* __restrict__ dmin,   // (B*npix) f32-bits
    uint2* __restrict__ pix_buf,       // (B*P) (pix, zcbits)
    uint4* __restrict__ tfeat,         // (B*P) x 4 uint4 (32 bf16)
    int P, int npix, int Hh, int Ww, int Bn)
{
    __shared__ unsigned int lds[32 * 129];   // 16.5 KB
    const int b = blockIdx.y;
    const int t = threadIdx.x;
    const int p0 = blockIdx.x * 256;
    if (p0 >= P) return;
    const size_t BP = (size_t)Bn * P;
    const size_t gbase = (size_t)b * P + p0;   // global point index of tile

    // ---- Phase A: project own point; persist (pix, zcbits); depth atomic
    //      deferred to kernel end (placement-neutral per R14, but harmless).
    bool valid = false;
    int pix = 0; float zc = 0.0f;
    {
        const int p = p0 + t;
        if (p < P) {
            valid = project_point(pc, K, E, nf, b, p, P, Hh, Ww, pix, zc);
            pix_buf[gbase + t] = make_uint2(valid ? (unsigned int)pix : PIX_INVALID,
                                            __float_as_uint(zc));
        }
    }

    // ---- Phase B: transpose this tile's features (streaming, BW-bound)
    const int tn = P - p0;
    if (tn >= 256) {
        #pragma unroll
        for (int k = 0; k < 8; ++k) {
            const int i = t + k * 256;          // 2048 float4 per tile
            const int c = i >> 6, col4 = i & 63;
            const vfloat4 v = __builtin_nontemporal_load(
                (const vfloat4*)(feats + (size_t)c * BP + gbase + (size_t)col4 * 4));
            const unsigned int w0 = f32_to_bf16_rne(v.x) | (f32_to_bf16_rne(v.y) << 16);
            const unsigned int w1 = f32_to_bf16_rne(v.z) | (f32_to_bf16_rne(v.w) << 16);
            lds[c * 129 + 2 * col4]     = w0;
            lds[c * 129 + 2 * col4 + 1] = w1;
        }
        __syncthreads();
        #pragma unroll
        for (int k = 0; k < 4; ++k) {
            const int o = t + k * 256;          // 1024 uint4 per tile
            const int pl = o >> 2, q = o & 3;
            const int wsel = pl >> 1;
            const int hsel = (pl & 1) * 16;
            unsigned int wd[4];
            #pragma unroll
            for (int m = 0; m < 4; ++m) {
                const int c0 = 8 * q + 2 * m;
                const unsigned int a  = lds[c0 * 129 + wsel];
                const unsigned int bb = lds[(c0 + 1) * 129 + wsel];
                wd[m] = ((a >> hsel) & 0xFFFFu) | (((bb >> hsel) & 0xFFFFu) << 16);
            }
            tfeat[gbase * 4 + o] = make_uint4(wd[0], wd[1], wd[2], wd[3]);
        }
    } else {
        if (t < tn) {
            const size_t p = gbase + t;
            #pragma unroll
            for (int grp = 0; grp < 4; ++grp) {
                unsigned int wd[4];
                #pragma unroll
                for (int kk = 0; kk < 4; ++kk) {
                    const int c0 = grp * 8 + 2 * kk;
                    wd[kk] = f32_to_bf16_rne(feats[(size_t)c0 * BP + p]) |
                             (f32_to_bf16_rne(feats[(size_t)(c0 + 1) * BP + p]) << 16);
                }
                tfeat[p * 4 + grp] = make_uint4(wd[0], wd[1], wd[2], wd[3]);
            }
        }
    }

    // ---- Deferred 32-bit depth atomic: fire-and-forget.
    if (valid) {
        atomicMin(&dmin[(size_t)b * npix + pix], __float_as_uint(zc));
    }
}

// ---------------------------------------------------------------------------
// Resolve pass: exact reference semantics. win = valid & (zc == dmin[pix]);
// idx[pix] = min pid among winners. Only depth-matchers (~winners+exact ties,
// ~35% of points) fire a 32-bit atomic; dmin reads are L3-hot (8 MB).
// Kernel boundary guarantees all pass-1 atomics completed.
// ---------------------------------------------------------------------------
__global__ void resolve_kernel(
    const uint2* __restrict__ pix_buf,  // (B*P) (pix, zcbits)
    const unsigned int* __restrict__ dmin,
    unsigned int* __restrict__ idx,     // (B*npix)
    int P, int npix)
{
    const int b = blockIdx.y;
    const int p = blockIdx.x * blockDim.x + threadIdx.x;
    if (p >= P) return;

    const uint2 pr = pix_buf[(size_t)b * P + p];
    if (pr.x == PIX_INVALID) return;
    if (dmin[(size_t)b * npix + pr.x] == pr.y) {
        atomicMin(&idx[(size_t)b * npix + pr.x], (unsigned int)p);
    }
}

// ---------------------------------------------------------------------------
// Gather + output: winner pid from idx -> ONE 64B line from tfeat (L3-hot);
// channel-plane writes NONTEMPORAL (never re-read).
// ---------------------------------------------------------------------------
__global__ void gather_output_kernel(
    const unsigned int* __restrict__ dmin,
    const unsigned int* __restrict__ idx,
    const uint4* __restrict__ tfeat,   // (BP) x 4 uint4
    const float* __restrict__ dflt,    // (C, 1)
    float* __restrict__ out_feat,      // (B, C, H, W)
    float* __restrict__ out_depth,     // (B, 1, H, W)
    int P, int npix)
{
    const int b = blockIdx.y;
    const int pix = blockIdx.x * blockDim.x + threadIdx.x;
    if (pix >= npix) return;

    const size_t gi = (size_t)b * npix + pix;
    const unsigned int ix = idx[gi];
    const bool empty = (ix == IDX_EMPTY);

    __builtin_nontemporal_store(
        empty ? 0.0f : __uint_as_float(dmin[gi]), out_depth + gi);

    float f[32];
    if (empty) {
        #pragma unroll
        for (int c = 0; c < 32; ++c) f[c] = dflt[c];
    } else {
        const uint4* src = tfeat + ((size_t)b * P + ix) * 4;
        #pragma unroll
        for (int q = 0; q < 4; ++q) {
            const uint4 v = src[q];
            const unsigned int ws[4] = {v.x, v.y, v.z, v.w};
            #pragma unroll
            for (int k = 0; k < 4; ++k) {
                f[q * 8 + 2 * k]     = bf16_bits_to_f32(ws[k] & 0xFFFFu);
                f[q * 8 + 2 * k + 1] = bf16_bits_to_f32(ws[k] >> 16);
            }
        }
    }

    float* of = out_feat + ((size_t)b * 32) * npix + pix;
    #pragma unroll
    for (int c = 0; c < 32; ++c)
        __builtin_nontemporal_store(f[c], of + (size_t)c * npix);
}

// ---------------------------------------------------------------------------
// Fallback path (ws too small or C != 32): 64-bit packed z-buffer + direct
// scatter, f32 exact. packed aliases the dmin/idx region (8 MB).
// ---------------------------------------------------------------------------
__global__ void init_packed_kernel(ulonglong2* __restrict__ packed, int n2)
{
    const int i = blockIdx.x * blockDim.x + threadIdx.x;
    if (i < n2) packed[i] = make_ulonglong2(~0ull, ~0ull);
}

__global__ void rasterize_fb_kernel(
    const float* __restrict__ pc, const float* __restrict__ K,
    const float* __restrict__ E, const float* __restrict__ nf,
    unsigned long long* __restrict__ packed,
    int P, int Hh, int Ww)
{
    const int b = blockIdx.y;
    const int p = blockIdx.x * blockDim.x + threadIdx.x;
    if (p >= P) return;
    int pix; float zc;
    if (!project_point(pc, K, E, nf, b, p, P, Hh, Ww, pix, zc)) return;
    const unsigned long long pk =
        ((unsigned long long)__float_as_uint(zc) << 32) | (unsigned int)p;
    atomicMin(&packed[(size_t)b * Hh * Ww + pix], pk);
}

__global__ void scatter_kernel(
    const float* __restrict__ pc, const float* __restrict__ K,
    const float* __restrict__ E, const float* __restrict__ nf,
    const unsigned long long* __restrict__ packed,
    const float* __restrict__ feats,
    float* __restrict__ out_feat,
    int B, int P, int C, int Hh, int Ww)
{
    const int b = blockIdx.y;
    const int p = blockIdx.x * blockDim.x + threadIdx.x;
    if (p >= P) return;
    int pix; float zc;
    if (!project_point(pc, K, E, nf, b, p, P, Hh, Ww, pix, zc)) return;
    const int npix = Hh * Ww;
    const unsigned long long pk = packed[(size_t)b * npix + pix];
    if ((unsigned int)(pk & 0xFFFFFFFFull) != (unsigned int)p) return;
    const size_t stride = (size_t)B * P;
    const size_t src0   = (size_t)b * P + p;
    float* of = out_feat + ((size_t)b * C) * npix + pix;
    for (int c = 0; c < C; ++c) of[(size_t)c * npix] = feats[(size_t)c * stride + src0];
}

__global__ void finalize_kernel(
    const unsigned long long* __restrict__ packed,
    const float* __restrict__ dflt,
    float* __restrict__ out_feat, float* __restrict__ out_depth,
    int C, int npix)
{
    const int b = blockIdx.y;
    const int pix = blockIdx.x * blockDim.x + threadIdx.x;
    if (pix >= npix) return;
    const size_t gi = (size_t)b * npix + pix;
    const unsigned long long pk = packed[gi];
    const bool empty = (pk == ~0ull);
    out_depth[gi] = empty ? 0.0f : __uint_as_float((unsigned int)(pk >> 32));
    if (empty) {
        float* of = out_feat + ((size_t)b * C) * npix + pix;
        for (int c = 0; c < C; ++c) of[(size_t)c * npix] = dflt[c];
    }
}

extern "C" void kernel_launch(void* const* d_in, const int* in_sizes, int n_in,
                              void* d_out, int out_size, void* d_ws, size_t ws_size,
                              hipStream_t stream) {
    const float* point_features = (const float*)d_in[0];  // (C, B*P)
    const float* default_feats  = (const float*)d_in[1];  // (C, 1)
    const float* point_clouds   = (const float*)d_in[2];  // (B*P, 3)
    const float* cam_K          = (const float*)d_in[3];  // (B, 3, 3)
    const float* cam_E          = (const float*)d_in[4];  // (B, 3, 4)
    const float* near_far       = (const float*)d_in[5];  // (B, 3)

    const int B  = in_sizes[3] / 9;
    const int BP = in_sizes[2] / 3;
    const int P  = BP / B;
    const int C  = in_sizes[0] / BP;
    const int Hh = 512, Ww = 512;
    const int npix = Hh * Ww;

    // d_ws layout: dmin (B*npix*4 = 4 MB) | idx (4 MB) | pix_buf (B*P*8 =
    // 16 MB) | tfeat (B*P*64 = 128 MB). Fallback aliases dmin/idx as packed.
    unsigned int* dmin = (unsigned int*)d_ws;
    unsigned int* idx  = dmin + (size_t)B * npix;
    uint2* pix_buf = (uint2*)((char*)d_ws + (size_t)B * npix * 8);
    uint4* tfeat = (uint4*)((char*)d_ws + (size_t)B * npix * 8 + (size_t)BP * 8);

    const size_t need = (size_t)B * npix * 8 + (size_t)BP * 8 + (size_t)BP * 64;

    float* out_feat  = (float*)d_out;                        // (B, C, H, W)
    float* out_depth = (float*)d_out + (size_t)B * C * npix; // (B, 1, H, W)

    const dim3 blk(TH);
    const dim3 grid_pts((P + TH - 1) / TH, B);
    const dim3 grid_pix((npix + TH - 1) / TH, B);

    if (ws_size >= need && C == 32) {
        const int n4 = (B * npix) / 4;
        init_zbuf_kernel<<<(n4 + TH - 1) / TH, blk, 0, stream>>>(
            (uint4*)dmin, (uint4*)idx, n4);
        fused_raster_transpose_kernel<<<grid_pts, blk, 0, stream>>>(
            point_clouds, cam_K, cam_E, near_far, point_features,
            dmin, pix_buf, tfeat, P, npix, Hh, Ww, B);
        resolve_kernel<<<grid_pts, blk, 0, stream>>>(
            pix_buf, dmin, idx, P, npix);
        gather_output_kernel<<<grid_pix, blk, 0, stream>>>(
            dmin, idx, tfeat, default_feats, out_feat, out_depth, P, npix);
    } else {
        unsigned long long* packed = (unsigned long long*)d_ws;  // aliases dmin/idx
        const int n2 = (B * npix) / 2;
        init_packed_kernel<<<(n2 + TH - 1) / TH, blk, 0, stream>>>(
            (ulonglong2*)packed, n2);
        rasterize_fb_kernel<<<grid_pts, blk, 0, stream>>>(
            point_clouds, cam_K, cam_E, near_far, packed, P, Hh, Ww);
        finalize_kernel<<<grid_pix, blk, 0, stream>>>(
            packed, default_feats, out_feat, out_depth, C, npix);
        scatter_kernel<<<grid_pts, blk, 0, stream>>>(
            point_clouds, cam_K, cam_E, near_far, packed, point_features,
            out_feat, B, P, C, Hh, Ww);
    }
}

// Round 17
// 139.181 us; speedup vs baseline: 1.2297x; 1.2297x over previous
//
#include <hip/hip_runtime.h>
#include <cstdint>
#include <cstddef>

// Problem constants (fixed by the harness): B=4, P=500000, C=32, H=512, W=512.
#define TH 256

// clang ext_vector_type: __builtin_nontemporal_load rejects HIP_vector_type
// (float4) pointers but accepts vectors of scalar types.
typedef float vfloat4 __attribute__((ext_vector_type(4)));

// ---------------------------------------------------------------------------
// FINAL STRUCTURE (R14, 139.9 us — best of 16 rounds):
//   init (3 us) -> fused raster+transpose (~110 us) -> gather (~26 us)
// Probed and rejected: occupancy x2 (R11 neutral), atomic placement (R14
// neutral), TILE=512 bursts (R15 -2), 32-bit split z-buffer (R16 +31),
// channel-major direct gather (R9 +107), early-reject atomics (R6 +30).
// Kept wins: pixel-major staging (R2), bf16 staging (R4), raster+transpose
// fusion (R10 -60), nontemporal streams (R13 -10).
// ---------------------------------------------------------------------------

// ---------------------------------------------------------------------------
// f32 <-> bf16 helpers (RNE). Unit-normal features: err ~0.02 << 0.2 thresh.
// (bf16 staging validated R4-R16: harness absmax 0.0 vs np ref.)
// ---------------------------------------------------------------------------
__device__ __forceinline__ unsigned int f32_to_bf16_rne(float x) {
    const unsigned int u = __float_as_uint(x);
    return (u + 0x7FFFu + ((u >> 16) & 1u)) >> 16;   // 16-bit result
}
__device__ __forceinline__ float bf16_bits_to_f32(unsigned int h) {
    return __uint_as_float(h << 16);
}

// ---------------------------------------------------------------------------
// Init: fill packed z-buffer with ~0 (streaming 16B stores, ~3 us).
// ---------------------------------------------------------------------------
__global__ void init_packed_kernel(ulonglong2* __restrict__ packed, int n2)
{
    const int i = blockIdx.x * blockDim.x + threadIdx.x;
    if (i < n2) packed[i] = make_ulonglong2(~0ull, ~0ull);
}

// ---------------------------------------------------------------------------
// Projection (shared): reproduces _rasterize_one's math in f32.
// ---------------------------------------------------------------------------
__device__ __forceinline__ bool project_point(
    const float* __restrict__ pc, const float* __restrict__ K,
    const float* __restrict__ E, const float* __restrict__ nf,
    int b, int p, int P, int Hh, int Ww,
    int& pix_out, float& zc_out)
{
    const int i = b * P + p;
    const float x = pc[3 * i + 0];
    const float y = pc[3 * i + 1];
    const float z = pc[3 * i + 2];
    const float* Eb = E + b * 12;
    const float dx = x - Eb[3], dy = y - Eb[7], dz = z - Eb[11];
    const float zc = dx * Eb[2] + dy * Eb[6] + dz * Eb[10];
    const float zs = (zc == 0.0f) ? 1.0f : zc;
    const float* Kb = K + b * 9;
    const float u = Kb[0] * (dx * Eb[0] + dy * Eb[4] + dz * Eb[8]) / zs + Kb[2];
    const float v = Kb[4] * (dx * Eb[1] + dy * Eb[5] + dz * Eb[9]) / zs + Kb[5];
    const int ui = (int)floorf(u);
    const int vi = (int)floorf(v);
    const float nf0 = nf[b * 3 + 0], nf1 = nf[b * 3 + 1];
    const bool valid = (zc > nf0) && (zc < nf1) &&
                       (ui >= 0) && (ui < Ww) && (vi >= 0) && (vi < Hh);
    pix_out = vi * Ww + ui;
    zc_out  = zc;
    return valid;
}

// ---------------------------------------------------------------------------
// FUSED rasterize + transpose (proven R14 form).
//   Phase A: project own point early (pc-load latency overlaps feats issue);
//            64-bit packed atomicMin fired at kernel end, fire-and-forget.
//   Phase B: bf16-LDS transpose (16.5 KB, 8 blocks/CU), nontemporal feats
//            reads (256 MB read-once stream must not evict tfeat from L3);
//            phase-2 LDS reads conflict-free via odd stride 129; uint4
//            stores lane-consecutive, line-exact.
// packed = (f32_bits(zc) << 32) | pid; atomicMin == (min depth, min pid)
// (positive f32 bits monotone; pid unique -> exact reference tie-break).
// ---------------------------------------------------------------------------
__global__ void fused_raster_transpose_kernel(
    const float* __restrict__ pc, const float* __restrict__ K,
    const float* __restrict__ E, const float* __restrict__ nf,
    const float* __restrict__ feats,   // (32, B*P)
    unsigned long long* __restrict__ packed,
    uint4* __restrict__ tfeat,         // (B*P) x 4 uint4 (32 bf16)
    int P, int npix, int Hh, int Ww, int Bn)
{
    __shared__ unsigned int lds[32 * 129];   // 16.5 KB
    const int b = blockIdx.y;
    const int t = threadIdx.x;
    const int p0 = blockIdx.x * 256;
    if (p0 >= P) return;
    const size_t BP = (size_t)Bn * P;
    const size_t gbase = (size_t)b * P + p0;   // global point index of tile

    // ---- Phase A: project own point EARLY; atomic deferred to kernel end.
    bool valid = false;
    int pix = 0; float zc = 0.0f;
    {
        const int p = p0 + t;
        if (p < P) valid = project_point(pc, K, E, nf, b, p, P, Hh, Ww, pix, zc);
    }

    // ---- Phase B: transpose this tile's features (streaming, BW-bound)
    const int tn = P - p0;
    if (tn >= 256) {
        #pragma unroll
        for (int k = 0; k < 8; ++k) {
            const int i = t + k * 256;          // 2048 float4 per tile
            const int c = i >> 6, col4 = i & 63;
            const vfloat4 v = __builtin_nontemporal_load(
                (const vfloat4*)(feats + (size_t)c * BP + gbase + (size_t)col4 * 4));
            const unsigned int w0 = f32_to_bf16_rne(v.x) | (f32_to_bf16_rne(v.y) << 16);
            const unsigned int w1 = f32_to_bf16_rne(v.z) | (f32_to_bf16_rne(v.w) << 16);
            lds[c * 129 + 2 * col4]     = w0;   // word 2*col4   = pts {4c4,4c4+1}
            lds[c * 129 + 2 * col4 + 1] = w1;   // word 2*col4+1 = pts {4c4+2,4c4+3}
        }
        __syncthreads();
        #pragma unroll
        for (int k = 0; k < 4; ++k) {
            const int o = t + k * 256;          // 1024 uint4 per tile
            const int pl = o >> 2, q = o & 3;
            const int wsel = pl >> 1;
            const int hsel = (pl & 1) * 16;
            unsigned int wd[4];
            #pragma unroll
            for (int m = 0; m < 4; ++m) {
                const int c0 = 8 * q + 2 * m;
                const unsigned int a  = lds[c0 * 129 + wsel];
                const unsigned int bb = lds[(c0 + 1) * 129 + wsel];
                wd[m] = ((a >> hsel) & 0xFFFFu) | (((bb >> hsel) & 0xFFFFu) << 16);
            }
            tfeat[gbase * 4 + o] = make_uint4(wd[0], wd[1], wd[2], wd[3]);
        }
    } else {
        // partial tail tile (P % 256): scalar per-point path
        if (t < tn) {
            const size_t p = gbase + t;
            #pragma unroll
            for (int grp = 0; grp < 4; ++grp) {
                unsigned int wd[4];
                #pragma unroll
                for (int kk = 0; kk < 4; ++kk) {
                    const int c0 = grp * 8 + 2 * kk;
                    wd[kk] = f32_to_bf16_rne(feats[(size_t)c0 * BP + p]) |
                             (f32_to_bf16_rne(feats[(size_t)(c0 + 1) * BP + p]) << 16);
                }
                tfeat[p * 4 + grp] = make_uint4(wd[0], wd[1], wd[2], wd[3]);
            }
        }
    }

    // ---- Deferred atomic: fire-and-forget; only wave-retire waits on it.
    if (valid) {
        const unsigned long long pk =
            ((unsigned long long)__float_as_uint(zc) << 32) |
            (unsigned int)(p0 + t);
        atomicMin(&packed[(size_t)b * npix + pix], pk);
    }
}

// ---------------------------------------------------------------------------
// Pass 3: pixel-parallel gather + output. Winner pid from packed low bits ->
// ONE 64B line from tfeat (L3-hot, nt-protected); channel-plane writes are
// NONTEMPORAL (outputs never re-read -> don't displace tfeat/packed in L3).
// ---------------------------------------------------------------------------
__global__ void gather_output_kernel(
    const unsigned long long* __restrict__ packed,
    const uint4* __restrict__ tfeat,   // (BP) x 4 uint4
    const float* __restrict__ dflt,    // (C, 1)
    float* __restrict__ out_feat,      // (B, C, H, W)
    float* __restrict__ out_depth,     // (B, 1, H, W)
    int P, int npix)
{
    const int b = blockIdx.y;
    const int pix = blockIdx.x * blockDim.x + threadIdx.x;
    if (pix >= npix) return;

    const size_t gi = (size_t)b * npix + pix;
    const unsigned long long pk = packed[gi];
    const bool empty = (pk == ~0ull);

    __builtin_nontemporal_store(
        empty ? 0.0f : __uint_as_float((unsigned int)(pk >> 32)),
        out_depth + gi);

    float f[32];
    if (empty) {
        #pragma unroll
        for (int c = 0; c < 32; ++c) f[c] = dflt[c];
    } else {
        const unsigned int pid = (unsigned int)(pk & 0xFFFFFFFFull);
        const uint4* src = tfeat + ((size_t)b * P + pid) * 4;
        #pragma unroll
        for (int q = 0; q < 4; ++q) {
            const uint4 v = src[q];
            const unsigned int ws[4] = {v.x, v.y, v.z, v.w};
            #pragma unroll
            for (int k = 0; k < 4; ++k) {
                f[q * 8 + 2 * k]     = bf16_bits_to_f32(ws[k] & 0xFFFFu);
                f[q * 8 + 2 * k + 1] = bf16_bits_to_f32(ws[k] >> 16);
            }
        }
    }

    float* of = out_feat + ((size_t)b * 32) * npix + pix;
    #pragma unroll
    for (int c = 0; c < 32; ++c)
        __builtin_nontemporal_store(f[c], of + (size_t)c * npix);
}

// ---------------------------------------------------------------------------
// Fallback path (ws too small or C != 32): direct scatter, f32 exact.
// ---------------------------------------------------------------------------
__global__ void rasterize_fb_kernel(
    const float* __restrict__ pc, const float* __restrict__ K,
    const float* __restrict__ E, const float* __restrict__ nf,
    unsigned long long* __restrict__ packed,
    int P, int Hh, int Ww)
{
    const int b = blockIdx.y;
    const int p = blockIdx.x * blockDim.x + threadIdx.x;
    if (p >= P) return;
    int pix; float zc;
    if (!project_point(pc, K, E, nf, b, p, P, Hh, Ww, pix, zc)) return;
    const unsigned long long pk =
        ((unsigned long long)__float_as_uint(zc) << 32) | (unsigned int)p;
    atomicMin(&packed[(size_t)b * Hh * Ww + pix], pk);
}

__global__ void scatter_kernel(
    const float* __restrict__ pc, const float* __restrict__ K,
    const float* __restrict__ E, const float* __restrict__ nf,
    const unsigned long long* __restrict__ packed,
    const float* __restrict__ feats,
    float* __restrict__ out_feat,
    int B, int P, int C, int Hh, int Ww)
{
    const int b = blockIdx.y;
    const int p = blockIdx.x * blockDim.x + threadIdx.x;
    if (p >= P) return;
    int pix; float zc;
    if (!project_point(pc, K, E, nf, b, p, P, Hh, Ww, pix, zc)) return;
    const int npix = Hh * Ww;
    const unsigned long long pk = packed[(size_t)b * npix + pix];
    if ((unsigned int)(pk & 0xFFFFFFFFull) != (unsigned int)p) return;
    const size_t stride = (size_t)B * P;
    const size_t src0   = (size_t)b * P + p;
    float* of = out_feat + ((size_t)b * C) * npix + pix;
    for (int c = 0; c < C; ++c) of[(size_t)c * npix] = feats[(size_t)c * stride + src0];
}

__global__ void finalize_kernel(
    const unsigned long long* __restrict__ packed,
    const float* __restrict__ dflt,
    float* __restrict__ out_feat, float* __restrict__ out_depth,
    int C, int npix)
{
    const int b = blockIdx.y;
    const int pix = blockIdx.x * blockDim.x + threadIdx.x;
    if (pix >= npix) return;
    const size_t gi = (size_t)b * npix + pix;
    const unsigned long long pk = packed[gi];
    const bool empty = (pk == ~0ull);
    out_depth[gi] = empty ? 0.0f : __uint_as_float((unsigned int)(pk >> 32));
    if (empty) {
        float* of = out_feat + ((size_t)b * C) * npix + pix;
        for (int c = 0; c < C; ++c) of[(size_t)c * npix] = dflt[c];
    }
}

extern "C" void kernel_launch(void* const* d_in, const int* in_sizes, int n_in,
                              void* d_out, int out_size, void* d_ws, size_t ws_size,
                              hipStream_t stream) {
    const float* point_features = (const float*)d_in[0];  // (C, B*P)
    const float* default_feats  = (const float*)d_in[1];  // (C, 1)
    const float* point_clouds   = (const float*)d_in[2];  // (B*P, 3)
    const float* cam_K          = (const float*)d_in[3];  // (B, 3, 3)
    const float* cam_E          = (const float*)d_in[4];  // (B, 3, 4)
    const float* near_far       = (const float*)d_in[5];  // (B, 3)

    const int B  = in_sizes[3] / 9;
    const int BP = in_sizes[2] / 3;
    const int P  = BP / B;
    const int C  = in_sizes[0] / BP;
    const int Hh = 512, Ww = 512;
    const int npix = Hh * Ww;

    // d_ws layout: packed (B*npix*8 = 8 MB) | tfeat (B*P*64 B = 128 MB)
    unsigned long long* packed = (unsigned long long*)d_ws;
    uint4* tfeat = (uint4*)((char*)d_ws + (size_t)B * npix * 8);

    const size_t need = (size_t)B * npix * 8 + (size_t)BP * 64;

    float* out_feat  = (float*)d_out;                        // (B, C, H, W)
    float* out_depth = (float*)d_out + (size_t)B * C * npix; // (B, 1, H, W)

    const dim3 blk(TH);
    const dim3 grid_pts((P + TH - 1) / TH, B);
    const dim3 grid_pix((npix + TH - 1) / TH, B);

    const int n2 = (B * npix) / 2;
    init_packed_kernel<<<(n2 + TH - 1) / TH, blk, 0, stream>>>(
        (ulonglong2*)packed, n2);

    if (ws_size >= need && C == 32) {
        fused_raster_transpose_kernel<<<grid_pts, blk, 0, stream>>>(
            point_clouds, cam_K, cam_E, near_far, point_features,
            packed, tfeat, P, npix, Hh, Ww, B);
        gather_output_kernel<<<grid_pix, blk, 0, stream>>>(
            packed, tfeat, default_feats, out_feat, out_depth, P, npix);
    } else {
        rasterize_fb_kernel<<<grid_pts, blk, 0, stream>>>(
            point_clouds, cam_K, cam_E, near_far, packed, P, Hh, Ww);
        finalize_kernel<<<grid_pix, blk, 0, stream>>>(
            packed, default_feats, out_feat, out_depth, C, npix);
        scatter_kernel<<<grid_pts, blk, 0, stream>>>(
            point_clouds, cam_K, cam_E, near_far, packed, point_features,
            out_feat, B, P, C, Hh, Ww);
    }
}